// Round 4
// baseline (2443.563 us; speedup 1.0000x reference)
//
#include <hip/hip_runtime.h>

#define B_ 256
#define S_ 80
#define H_ 512
#define V_ 4096
#define NSTEP 27

typedef unsigned short u16;
typedef __attribute__((ext_vector_type(8))) short short8v;
typedef __attribute__((ext_vector_type(4))) float f32x4;
typedef __attribute__((ext_vector_type(4))) unsigned short ushort4v;

#define MFMA_(a,b,c) __builtin_amdgcn_mfma_f32_16x16x32_bf16(a,b,c,0,0,0)
#define MFMA3(acc, ah, al, bh, bl) do{ acc = MFMA_(ah,bh,acc); acc = MFMA_(ah,bl,acc); acc = MFMA_(al,bh,acc);}while(0)

__device__ __forceinline__ unsigned fkey(float v){
    unsigned u = __float_as_uint(v);
    return (u & 0x80000000u) ? ~u : (u | 0x80000000u);
}
__device__ __forceinline__ u16 bf16_rne(float f){
    unsigned u = __float_as_uint(f);
    return (u16)((u + 0x7FFFu + ((u >> 16) & 1u)) >> 16);
}
__device__ __forceinline__ void split_f4(float4 v, ushort4v& hi, ushort4v& lo){
    float arr[4] = {v.x, v.y, v.z, v.w};
    ushort4v h, l;
#pragma unroll
    for (int i = 0; i < 4; ++i){
        u16 hb = bf16_rne(arr[i]);
        h[i] = hb;
        l[i] = bf16_rne(arr[i] - __uint_as_float(((unsigned)hb) << 16));
    }
    hi = h; lo = l;
}

// ---------------- front ----------------
__global__ __launch_bounds__(64) void matvec512(const float* __restrict__ W,
                                                const float* __restrict__ v,
                                                float* __restrict__ out){
    int row = blockIdx.x, lane = threadIdx.x;
    const float* wr = W + row * 512;
    float s = 0.f;
#pragma unroll
    for (int i = 0; i < 8; ++i) s += wr[lane + 64*i] * v[lane + 64*i];
#pragma unroll
    for (int off = 32; off; off >>= 1) s += __shfl_xor(s, off);
    if (lane == 0) out[row] = s;
}

__global__ __launch_bounds__(256) void score_kernel(const float* __restrict__ enc,
                                                    const float* __restrict__ weff,
                                                    float* __restrict__ scores){
    int wv = threadIdx.x >> 6, lane = threadIdx.x & 63;
    int p = blockIdx.x * 4 + wv;
    const float* e = enc + (size_t)p * 512;
    float s = 0.f;
#pragma unroll
    for (int i = 0; i < 8; ++i) s += e[lane + 64*i] * weff[lane + 64*i];
#pragma unroll
    for (int off = 32; off; off >>= 1) s += __shfl_xor(s, off);
    if (lane == 0) scores[p] = s;
}

__global__ __launch_bounds__(512) void softmax_ctx(const float* __restrict__ enc,
                                                   const float* __restrict__ scores,
                                                   float* __restrict__ ctx){
    __shared__ float att[S_];
    int b = blockIdx.x, tid = threadIdx.x;
    if (tid < S_) att[tid] = scores[b*S_ + tid];
    __syncthreads();
    if (tid == 0){
        float mx = att[0];
        for (int s = 1; s < S_; ++s) mx = fmaxf(mx, att[s]);
        float sum = 0.f;
        for (int s = 0; s < S_; ++s){ float e = expf(att[s] - mx); att[s] = e; sum += e; }
        float inv = 1.f / sum;
        for (int s = 0; s < S_; ++s) att[s] *= inv;
    }
    __syncthreads();
    float a = 0.f;
    const float* eb = enc + (size_t)b * (S_*H_);
    for (int s = 0; s < S_; ++s) a += att[s] * eb[s*H_ + tid];
    ctx[b*H_ + tid] = a;
}

template<int TM>
__global__ __launch_bounds__(256) void gemm_abt(const float* __restrict__ A, int lda,
                                                const float* __restrict__ Bm, int ldb,
                                                const float* __restrict__ bias,
                                                float* __restrict__ C, int ldc, int K){
    constexpr int RPT = TM / 16;
    __shared__ float As[16][TM + 4];
    __shared__ float Bs[16][64 + 4];
    int m0 = blockIdx.x * TM, n0 = blockIdx.y * 64;
    int tid = threadIdx.x;
    int lk = tid & 15, lr = tid >> 4;
    int tx = tid & 15, ty = tid >> 4;
    float c[RPT][4] = {};
    for (int k0 = 0; k0 < K; k0 += 16){
#pragma unroll
        for (int i = 0; i < RPT; ++i)
            As[lk][lr*RPT + i] = A[(size_t)(m0 + lr*RPT + i)*lda + k0 + lk];
#pragma unroll
        for (int i = 0; i < 4; ++i)
            Bs[lk][lr*4 + i] = Bm[(size_t)(n0 + lr*4 + i)*ldb + k0 + lk];
        __syncthreads();
#pragma unroll
        for (int k = 0; k < 16; ++k){
            float b4[4];
            *(float4*)b4 = *(const float4*)&Bs[k][tx*4];
#pragma unroll
            for (int i = 0; i < RPT; ++i){
                float a = As[k][ty*RPT + i];
#pragma unroll
                for (int j = 0; j < 4; ++j) c[i][j] += a * b4[j];
            }
        }
        __syncthreads();
    }
#pragma unroll
    for (int j = 0; j < 4; ++j){
        float bb = bias ? bias[n0 + tx*4 + j] : 0.f;
#pragma unroll
        for (int i = 0; i < RPT; ++i)
            C[(size_t)(m0 + ty*RPT + i)*ldc + n0 + tx*4 + j] = c[i][j] + bb;
    }
}

// ---------------- one-time transforms ----------------
__global__ __launch_bounds__(256) void split_mat(const float* __restrict__ src,
                                                 u16* __restrict__ hi, u16* __restrict__ lo){
    int idx = (blockIdx.x * 256 + threadIdx.x) * 4;
    float4 v = *(const float4*)&src[idx];
    ushort4v h, l; split_f4(v, h, l);
    *(ushort4v*)&hi[idx] = h;
    *(ushort4v*)&lo[idx] = l;
}

// Wih rows x cols[0:1024] (ld 1536) -> compact 1024-wide splits
__global__ __launch_bounds__(256) void split_rows1024(const float* __restrict__ src,
                                                      u16* __restrict__ hi, u16* __restrict__ lo){
    int id = (blockIdx.x * 256 + threadIdx.x) * 4;
    int r = id >> 10, c = id & 1023;
    float4 v = *(const float4*)&src[(size_t)r*1536 + c];
    ushort4v h, l; split_f4(v, h, l);
    *(ushort4v*)&hi[id] = h;
    *(ushort4v*)&lo[id] = l;
}

__global__ __launch_bounds__(256) void wo_split(const float* __restrict__ Wo,
                                                u16* __restrict__ Thi, u16* __restrict__ Tlo){
    __shared__ float T[64][65];
    int k0 = blockIdx.x * 64, n0 = blockIdx.y * 64;
    int tid = threadIdx.x;
#pragma unroll
    for (int i = 0; i < 16; ++i){
        int idx = tid + i*256;
        int kk = idx >> 6, nn = idx & 63;
        T[kk][nn] = Wo[(size_t)(k0+kk)*4096 + n0+nn];
    }
    __syncthreads();
#pragma unroll
    for (int i = 0; i < 16; ++i){
        int idx = tid + i*256;
        int nn = idx >> 6, kk = idx & 63;
        float v = T[kk][nn];
        u16 hi = bf16_rne(v);
        u16 lo = bf16_rne(v - __uint_as_float(((unsigned)hi) << 16));
        size_t o = (size_t)(n0+nn)*512 + k0+kk;
        Thi[o] = hi; Tlo[o] = lo;
    }
}

__global__ __launch_bounds__(256) void zero_u32(unsigned* __restrict__ p, int n){
    int i = blockIdx.x * 256 + threadIdx.x;
    if (i < n) p[i] = 0u;
}

// ---------------- Eproj: emb(4096x1024) @ WihL^T(1536x1024), u16 inputs ----------------
__global__ __launch_bounds__(256) void eproj_u16(const u16* __restrict__ Ahi, const u16* __restrict__ Alo,
                                                 const u16* __restrict__ Bhi, const u16* __restrict__ Blo,
                                                 float* __restrict__ C){
    __shared__ u16 Ah[64][40], Al[64][40], Bh[64][40], Bl[64][40];
    int n0 = blockIdx.x * 64, m0 = blockIdx.y * 64;
    int tid = threadIdx.x, lane = tid & 63, wid = tid >> 6;
    int wm = (wid & 1) * 32, wn = (wid >> 1) * 32;
    int l15 = lane & 15, lk = (lane >> 4) * 8;
    f32x4 acc[2][2] = {};
    short8v ra[2], rb[2];
#pragma unroll
    for (int j = 0; j < 2; ++j){
        int c = j*256 + tid;
        int half = c >> 8, i = c & 255, row = i >> 2, k8 = (i & 3)*8;
        ra[j] = *(const short8v*)&(half ? Alo : Ahi)[(size_t)(m0+row)*1024 + k8];
        rb[j] = *(const short8v*)&(half ? Blo : Bhi)[(size_t)(n0+row)*1024 + k8];
    }
    for (int k0 = 0; k0 < 1024; k0 += 32){
        __syncthreads();
#pragma unroll
        for (int j = 0; j < 2; ++j){
            int c = j*256 + tid;
            int half = c >> 8, i = c & 255, row = i >> 2, k8 = (i & 3)*8;
            if (half){ *(short8v*)&Al[row][k8] = ra[j]; *(short8v*)&Bl[row][k8] = rb[j]; }
            else     { *(short8v*)&Ah[row][k8] = ra[j]; *(short8v*)&Bh[row][k8] = rb[j]; }
        }
        __syncthreads();
        if (k0 + 32 < 1024){
#pragma unroll
            for (int j = 0; j < 2; ++j){
                int c = j*256 + tid;
                int half = c >> 8, i = c & 255, row = i >> 2, k8 = (i & 3)*8;
                ra[j] = *(const short8v*)&(half ? Alo : Ahi)[(size_t)(m0+row)*1024 + k0+32 + k8];
                rb[j] = *(const short8v*)&(half ? Blo : Bhi)[(size_t)(n0+row)*1024 + k0+32 + k8];
            }
        }
        short8v ah0 = *(const short8v*)&Ah[wm +  0 + l15][lk];
        short8v ah1 = *(const short8v*)&Ah[wm + 16 + l15][lk];
        short8v al0 = *(const short8v*)&Al[wm +  0 + l15][lk];
        short8v al1 = *(const short8v*)&Al[wm + 16 + l15][lk];
        short8v bh0 = *(const short8v*)&Bh[wn +  0 + l15][lk];
        short8v bh1 = *(const short8v*)&Bh[wn + 16 + l15][lk];
        short8v bl0 = *(const short8v*)&Bl[wn +  0 + l15][lk];
        short8v bl1 = *(const short8v*)&Bl[wn + 16 + l15][lk];
        MFMA3(acc[0][0], ah0, al0, bh0, bl0);
        MFMA3(acc[0][1], ah0, al0, bh1, bl1);
        MFMA3(acc[1][0], ah1, al1, bh0, bl0);
        MFMA3(acc[1][1], ah1, al1, bh1, bl1);
    }
    int col0 = n0 + wn + l15;
    int rg = lane >> 4;
#pragma unroll
    for (int mf = 0; mf < 2; ++mf)
#pragma unroll
        for (int r = 0; r < 4; ++r){
            int row = m0 + wm + mf*16 + rg*4 + r;
            C[(size_t)row*1536 + col0]      = acc[mf][0][r];
            C[(size_t)row*1536 + col0 + 16] = acc[mf][1][r];
        }
}

// ---------------- persistent decode: all 27 steps, flag-synced ----------------
__global__ __launch_bounds__(256, 2) void decode_persist(
    const float* __restrict__ elhs,
    float* __restrict__ Hf,                 // [2][B_*H_]
    u16* __restrict__ Sh, u16* __restrict__ Sl,   // [2][B_*H_]
    const u16* __restrict__ WhhHi, const u16* __restrict__ WhhLo,
    const float* __restrict__ bhh,
    const float* __restrict__ Eproj, const float* __restrict__ gictx,
    const u16* __restrict__ WoHi, const u16* __restrict__ WoLo,
    const float* __restrict__ bo,
    unsigned long long* __restrict__ P,     // [27][256] pre-zeroed
    unsigned* __restrict__ cntA, unsigned* __restrict__ cntB, // [27][8] pre-zeroed
    float* __restrict__ logits, float* __restrict__ preds)
{
    __shared__ __align__(16) char smem[25728];
    u16 (*Ah)[40] = (u16(*)[40])(smem);
    u16 (*Al)[40] = (u16(*)[40])(smem + 2560);
    int* widx = (int*)(smem + 25600);
    const int tid = threadIdx.x;
    const int bid = blockIdx.x;
    const int lane = tid & 63, wid = tid >> 6;
    const int l15 = lane & 15, lk = (lane >> 4) * 8, rg = lane >> 4;

    for (int t = 0; t < NSTEP; ++t){
        const int pr = t & 1, pw = (t + 1) & 1;
        const float* hin = (t == 0) ? elhs : (Hf + (size_t)pr * 131072);
        float* hout = Hf + (size_t)pw * 131072;
        u16* ShW = Sh + (size_t)pw * 131072;
        u16* SlW = Sl + (size_t)pw * 131072;

        if (bid < 128){
            // ---- phase A: gh MFMA + GRU pointwise; tile 32 rows x 32 j ----
            u16 (*Bh)[40] = (u16(*)[40])(smem + 5120);
            u16 (*Bl)[40] = (u16(*)[40])(smem + 12800);
            int g = bid >> 4, jblk = bid & 15;
            int m0 = g * 32, j0 = jblk * 32;
            if (t > 0){
                if (tid == 0){
                    while (__hip_atomic_load(&cntA[(t-1)*8+g], __ATOMIC_ACQUIRE, __HIP_MEMORY_SCOPE_AGENT) < 16u)
                        __builtin_amdgcn_s_sleep(2);
                    while (__hip_atomic_load(&cntB[(t-1)*8+g], __ATOMIC_ACQUIRE, __HIP_MEMORY_SCOPE_AGENT) < 32u)
                        __builtin_amdgcn_s_sleep(2);
                }
            }
            __syncthreads();
            if (tid < 32){
                int b = m0 + tid;
                int w = 1;
                if (t > 0){
                    w = 4095 - (int)(P[(t-1)*256 + b] & 0xFFFFFFFFull);
                    if (w < 0) w = 0; if (w > 4095) w = 4095;
                    if (jblk == 0) preds[b*NSTEP + (t-1)] = (float)w;
                }
                widx[tid] = w;
            }
            int arow = tid >> 3, ak = (tid & 7) * 4;
            int wm = (wid & 1) * 16, wj = (wid >> 1) * 16;
            f32x4 acc[3] = {};
            float4 aR = *(const float4*)&hin[(size_t)(m0+arow)*512 + ak];
            short8v bR[3];
#pragma unroll
            for (int i = 0; i < 3; ++i){
                int c = tid + i*256;
                int s = (c >= 384); int cc = c - s*384;
                int r = cc >> 2, k8 = (cc & 3) * 8;
                int grow = (r >> 5)*512 + j0 + (r & 31);
                bR[i] = *(const short8v*)&(s ? WhhLo : WhhHi)[(size_t)grow*512 + k8];
            }
            for (int k0 = 0; k0 < 512; k0 += 32){
                __syncthreads();
                ushort4v h4, l4; split_f4(aR, h4, l4);
                *(ushort4v*)&Ah[arow][ak] = h4;
                *(ushort4v*)&Al[arow][ak] = l4;
#pragma unroll
                for (int i = 0; i < 3; ++i){
                    int c = tid + i*256;
                    int s = (c >= 384); int cc = c - s*384;
                    int r = cc >> 2, k8 = (cc & 3) * 8;
                    if (s) *(short8v*)&Bl[r][k8] = bR[i];
                    else   *(short8v*)&Bh[r][k8] = bR[i];
                }
                __syncthreads();
                if (k0 + 32 < 512){
                    aR = *(const float4*)&hin[(size_t)(m0+arow)*512 + k0+32 + ak];
#pragma unroll
                    for (int i = 0; i < 3; ++i){
                        int c = tid + i*256;
                        int s = (c >= 384); int cc = c - s*384;
                        int r = cc >> 2, k8 = (cc & 3) * 8;
                        int grow = (r >> 5)*512 + j0 + (r & 31);
                        bR[i] = *(const short8v*)&(s ? WhhLo : WhhHi)[(size_t)grow*512 + k0+32 + k8];
                    }
                }
                short8v ah = *(const short8v*)&Ah[wm + l15][lk];
                short8v al = *(const short8v*)&Al[wm + l15][lk];
#pragma unroll
                for (int gg = 0; gg < 3; ++gg){
                    short8v bh = *(const short8v*)&Bh[gg*32 + wj + l15][lk];
                    short8v bl = *(const short8v*)&Bl[gg*32 + wj + l15][lk];
                    MFMA3(acc[gg], ah, al, bh, bl);
                }
            }
            int jg = j0 + wj + l15;
            float br_ = bhh[jg], bz_ = bhh[512 + jg], bn_ = bhh[1024 + jg];
#pragma unroll
            for (int r = 0; r < 4; ++r){
                int rl = wm + rg*4 + r;
                int row = m0 + rl;
                int w = widx[rl];
                const float* ep = Eproj + (size_t)w * 1536;
                const float* gc = gictx + (size_t)row * 1536;
                float gir = ep[jg]        + gc[jg]        + acc[0][r] + br_;
                float giz = ep[512 + jg]  + gc[512 + jg]  + acc[1][r] + bz_;
                float gin = ep[1024 + jg] + gc[1024 + jg];
                float rr = 1.f / (1.f + expf(-gir));
                float zz = 1.f / (1.f + expf(-giz));
                float nn = tanhf(gin + rr * (acc[2][r] + bn_));
                float hold = hin[(size_t)row*512 + jg];
                float val = (1.f - zz)*nn + zz*hold;
                size_t idx = (size_t)row*512 + jg;
                hout[idx] = val;
                u16 hb = bf16_rne(val);
                ShW[idx] = hb;
                SlW[idx] = bf16_rne(val - __uint_as_float(((unsigned)hb) << 16));
            }
            __syncthreads();
            if (tid == 0){ __threadfence(); __hip_atomic_fetch_add(&cntA[t*8+g], 1u, __ATOMIC_RELEASE, __HIP_MEMORY_SCOPE_AGENT); }
        }

        // ---- phase B: logits tile 32 rows x 128 cols + fused argmax ----
        {
            u16 (*Bh)[40] = (u16(*)[40])(smem + 5120);
            u16 (*Bl)[40] = (u16(*)[40])(smem + 15360);
            int g = bid >> 5, nblk = bid & 31;
            int m0 = g * 32, n0 = nblk * 128;
            if (tid == 0){
                while (__hip_atomic_load(&cntA[t*8+g], __ATOMIC_ACQUIRE, __HIP_MEMORY_SCOPE_AGENT) < 16u)
                    __builtin_amdgcn_s_sleep(2);
            }
            __syncthreads();
            int ahalf = tid >> 7, ai = tid & 127;
            int sarow = ai >> 2, sak8 = (ai & 3) * 8;
            const u16* Asrc = ahalf ? SlW : ShW;
            int wn = wid * 32;
            f32x4 acc[2][2] = {};
            short8v raA = *(const short8v*)&Asrc[(size_t)(m0+sarow)*512 + sak8];
            short8v rB[4];
#pragma unroll
            for (int j = 0; j < 4; ++j){
                int c = j*256 + tid;
                int half = c >> 9, i = c & 511, row = i >> 2, k8 = (i & 3)*8;
                rB[j] = *(const short8v*)&(half ? WoLo : WoHi)[(size_t)(n0+row)*512 + k8];
            }
            for (int k0 = 0; k0 < 512; k0 += 32){
                __syncthreads();
                if (ahalf) *(short8v*)&Al[sarow][sak8] = raA;
                else       *(short8v*)&Ah[sarow][sak8] = raA;
#pragma unroll
                for (int j = 0; j < 4; ++j){
                    int c = j*256 + tid;
                    int half = c >> 9, i = c & 511, row = i >> 2, k8 = (i & 3)*8;
                    if (half) *(short8v*)&Bl[row][k8] = rB[j];
                    else      *(short8v*)&Bh[row][k8] = rB[j];
                }
                __syncthreads();
                if (k0 + 32 < 512){
                    raA = *(const short8v*)&Asrc[(size_t)(m0+sarow)*512 + k0+32 + sak8];
#pragma unroll
                    for (int j = 0; j < 4; ++j){
                        int c = j*256 + tid;
                        int half = c >> 9, i = c & 511, row = i >> 2, k8 = (i & 3)*8;
                        rB[j] = *(const short8v*)&(half ? WoLo : WoHi)[(size_t)(n0+row)*512 + k0+32 + k8];
                    }
                }
                short8v ah0 = *(const short8v*)&Ah[ 0 + l15][lk];
                short8v ah1 = *(const short8v*)&Ah[16 + l15][lk];
                short8v al0 = *(const short8v*)&Al[ 0 + l15][lk];
                short8v al1 = *(const short8v*)&Al[16 + l15][lk];
                short8v bh0 = *(const short8v*)&Bh[wn +  0 + l15][lk];
                short8v bh1 = *(const short8v*)&Bh[wn + 16 + l15][lk];
                short8v bl0 = *(const short8v*)&Bl[wn +  0 + l15][lk];
                short8v bl1 = *(const short8v*)&Bl[wn + 16 + l15][lk];
                MFMA3(acc[0][0], ah0, al0, bh0, bl0);
                MFMA3(acc[0][1], ah0, al0, bh1, bl1);
                MFMA3(acc[1][0], ah1, al1, bh0, bl0);
                MFMA3(acc[1][1], ah1, al1, bh1, bl1);
            }
            int col0 = n0 + wn + l15;
            float bo0 = bo[col0], bo1 = bo[col0 + 16];
            float* Ct = logits + (size_t)t * V_;
#pragma unroll
            for (int mf = 0; mf < 2; ++mf)
#pragma unroll
                for (int r = 0; r < 4; ++r){
                    int row = m0 + mf*16 + rg*4 + r;
                    float v0 = acc[mf][0][r] + bo0;
                    float v1 = acc[mf][1][r] + bo1;
                    float* crow = Ct + (size_t)row * (NSTEP * (size_t)V_);
                    crow[col0]      = v0;
                    crow[col0 + 16] = v1;
                    unsigned long long pk0 = ((unsigned long long)fkey(v0) << 32) | (unsigned)(4095 - col0);
                    unsigned long long pk1 = ((unsigned long long)fkey(v1) << 32) | (unsigned)(4095 - (col0+16));
                    unsigned long long best = pk0 > pk1 ? pk0 : pk1;
#pragma unroll
                    for (int off = 1; off < 16; off <<= 1){
                        unsigned long long o = __shfl_xor(best, off);
                        if (o > best) best = o;
                    }
                    if (l15 == 0) atomicMax(&P[t*256 + row], best);
                }
            __syncthreads();
            if (tid == 0){ __threadfence(); __hip_atomic_fetch_add(&cntB[t*8+g], 1u, __ATOMIC_RELEASE, __HIP_MEMORY_SCOPE_AGENT); }
        }
    }
    // final predictions column (t = 26)
    if (bid < 8){
        if (tid == 0){
            while (__hip_atomic_load(&cntB[26*8+bid], __ATOMIC_ACQUIRE, __HIP_MEMORY_SCOPE_AGENT) < 32u)
                __builtin_amdgcn_s_sleep(2);
        }
        __syncthreads();
        if (tid < 32){
            int row = bid*32 + tid;
            int w = 4095 - (int)(P[26*256 + row] & 0xFFFFFFFFull);
            if (w < 0) w = 0; if (w > 4095) w = 4095;
            preds[row*NSTEP + 26] = (float)w;
        }
    }
}

extern "C" void kernel_launch(void* const* d_in, const int* in_sizes, int n_in,
                              void* d_out, int out_size, void* d_ws, size_t ws_size,
                              hipStream_t stream){
    const float* elhs = (const float*)d_in[0];
    const float* enc  = (const float*)d_in[1];
    const float* emb  = (const float*)d_in[3];
    const float* W1   = (const float*)d_in[4];
    const float* W2   = (const float*)d_in[6];
    const float* W3   = (const float*)d_in[8];
    const float* W4   = (const float*)d_in[10];
    const float* Ww   = (const float*)d_in[12];
    const float* Wih  = (const float*)d_in[13];
    const float* bih  = (const float*)d_in[14];
    const float* Whh  = (const float*)d_in[15];
    const float* bhh  = (const float*)d_in[16];
    const float* Wo   = (const float*)d_in[17];
    const float* bo   = (const float*)d_in[18];

    float* out = (float*)d_out;
    float* preds = out + (size_t)B_ * NSTEP * V_;

    float* ws = (float*)d_ws;
    float* Eproj  = ws;  ws += (size_t)V_ * 1536;
    float* gictx  = ws;  ws += (size_t)B_ * 1536;
    float* ctx    = ws;  ws += B_ * H_;
    float* scores = ws;  ws += B_ * S_;
    float* t1     = ws;  ws += 512;
    float* t2     = ws;  ws += 512;
    float* weff   = ws;  ws += 512;
    float* Hf     = ws;  ws += 2 * B_ * H_;
    u16* WoT_hi = (u16*)ws;  ws += (size_t)V_ * 512 / 2;
    u16* WoT_lo = (u16*)ws;  ws += (size_t)V_ * 512 / 2;
    u16* WhhHi  = (u16*)ws;  ws += 1536 * 512 / 2;
    u16* WhhLo  = (u16*)ws;  ws += 1536 * 512 / 2;
    u16* Sh     = (u16*)ws;  ws += 2 * B_ * H_ / 2;
    u16* Sl     = (u16*)ws;  ws += 2 * B_ * H_ / 2;
    // contiguous sync region: P [27*256 u64] then cntA, cntB [27*8 u32 each]
    unsigned long long* P = (unsigned long long*)ws;
    unsigned* cntA = (unsigned*)(P + NSTEP*256);
    unsigned* cntB = cntA + NSTEP*8;

    // scratch splits parked in d_out tail-free region (consumed before logits written)
    u16* EmbHi  = (u16*)d_out;                       // 4096x1024
    u16* EmbLo  = EmbHi + (size_t)V_*1024;
    u16* WihLHi = EmbLo + (size_t)V_*1024;           // 1536x1024 compact
    u16* WihLLo = WihLHi + (size_t)1536*1024;

    // one-time transforms
    split_mat<<<1536*512/(4*256), 256, 0, stream>>>(Whh, WhhHi, WhhLo);
    { dim3 g(512/64, V_/64); wo_split<<<g, 256, 0, stream>>>(Wo, WoT_hi, WoT_lo); }
    split_mat<<<V_*1024/(4*256), 256, 0, stream>>>(emb, EmbHi, EmbLo);
    split_rows1024<<<1536*1024/(4*256), 256, 0, stream>>>(Wih, WihLHi, WihLLo);
    zero_u32<<<(NSTEP*256*2 + NSTEP*8*2 + 255)/256, 256, 0, stream>>>((unsigned*)P, NSTEP*256*2 + NSTEP*8*2);

    // front: collapsed attention (h-independent), context, gi_ctx
    matvec512<<<512, 64, 0, stream>>>(W4, Ww, t1);
    matvec512<<<512, 64, 0, stream>>>(W3, t1, t2);
    matvec512<<<512, 64, 0, stream>>>(W2, t2, t1);
    matvec512<<<512, 64, 0, stream>>>(W1, t1, weff);
    score_kernel<<<(B_*S_)/4, 256, 0, stream>>>(enc, weff, scores);
    softmax_ctx<<<B_, 512, 0, stream>>>(enc, scores, ctx);
    { dim3 g(B_/32, 1536/64);
      gemm_abt<32><<<g, 256, 0, stream>>>(ctx, 512, Wih + 1024, 1536, bih, gictx, 1536, 512); }
    { dim3 g(1536/64, V_/64);
      eproj_u16<<<g, 256, 0, stream>>>(EmbHi, EmbLo, WihLHi, WihLLo, Eproj); }

    // the whole 27-step decode in one persistent kernel
    decode_persist<<<256, 256, 0, stream>>>(elhs, Hf, Sh, Sl, WhhHi, WhhLo, bhh,
                                            Eproj, gictx, WoT_hi, WoT_lo, bo,
                                            P, cntA, cntB, out, preds);
}

// Round 5
// 1775.123 us; speedup vs baseline: 1.3766x; 1.3766x over previous
//
#include <hip/hip_runtime.h>

#define B_ 256
#define S_ 80
#define H_ 512
#define V_ 4096
#define NSTEP 27

typedef unsigned short u16;
typedef __attribute__((ext_vector_type(8))) short short8v;
typedef __attribute__((ext_vector_type(4))) float f32x4;
typedef __attribute__((ext_vector_type(4))) unsigned short ushort4v;

#define MFMA_(a,b,c) __builtin_amdgcn_mfma_f32_16x16x32_bf16(a,b,c,0,0,0)
#define MFMA3(acc, ah, al, bh, bl) do{ acc = MFMA_(ah,bh,acc); acc = MFMA_(ah,bl,acc); acc = MFMA_(al,bh,acc);}while(0)

__device__ __forceinline__ unsigned fkey(float v){
    unsigned u = __float_as_uint(v);
    return (u & 0x80000000u) ? ~u : (u | 0x80000000u);
}
__device__ __forceinline__ u16 bf16_rne(float f){
    unsigned u = __float_as_uint(f);
    return (u16)((u + 0x7FFFu + ((u >> 16) & 1u)) >> 16);
}
__device__ __forceinline__ void split_f4(float4 v, ushort4v& hi, ushort4v& lo){
    float arr[4] = {v.x, v.y, v.z, v.w};
    ushort4v h, l;
#pragma unroll
    for (int i = 0; i < 4; ++i){
        u16 hb = bf16_rne(arr[i]);
        h[i] = hb;
        l[i] = bf16_rne(arr[i] - __uint_as_float(((unsigned)hb) << 16));
    }
    hi = h; lo = l;
}

// ---------------- front ----------------
__global__ __launch_bounds__(64) void matvec512(const float* __restrict__ W,
                                                const float* __restrict__ v,
                                                float* __restrict__ out){
    int row = blockIdx.x, lane = threadIdx.x;
    const float* wr = W + row * 512;
    float s = 0.f;
#pragma unroll
    for (int i = 0; i < 8; ++i) s += wr[lane + 64*i] * v[lane + 64*i];
#pragma unroll
    for (int off = 32; off; off >>= 1) s += __shfl_xor(s, off);
    if (lane == 0) out[row] = s;
}

__global__ __launch_bounds__(256) void score_kernel(const float* __restrict__ enc,
                                                    const float* __restrict__ weff,
                                                    float* __restrict__ scores){
    int wv = threadIdx.x >> 6, lane = threadIdx.x & 63;
    int p = blockIdx.x * 4 + wv;
    const float* e = enc + (size_t)p * 512;
    float s = 0.f;
#pragma unroll
    for (int i = 0; i < 8; ++i) s += e[lane + 64*i] * weff[lane + 64*i];
#pragma unroll
    for (int off = 32; off; off >>= 1) s += __shfl_xor(s, off);
    if (lane == 0) scores[p] = s;
}

__global__ __launch_bounds__(512) void softmax_ctx(const float* __restrict__ enc,
                                                   const float* __restrict__ scores,
                                                   float* __restrict__ ctx){
    __shared__ float att[S_];
    int b = blockIdx.x, tid = threadIdx.x;
    if (tid < S_) att[tid] = scores[b*S_ + tid];
    __syncthreads();
    if (tid == 0){
        float mx = att[0];
        for (int s = 1; s < S_; ++s) mx = fmaxf(mx, att[s]);
        float sum = 0.f;
        for (int s = 0; s < S_; ++s){ float e = expf(att[s] - mx); att[s] = e; sum += e; }
        float inv = 1.f / sum;
        for (int s = 0; s < S_; ++s) att[s] *= inv;
    }
    __syncthreads();
    float a = 0.f;
    const float* eb = enc + (size_t)b * (S_*H_);
    for (int s = 0; s < S_; ++s) a += att[s] * eb[s*H_ + tid];
    ctx[b*H_ + tid] = a;
}

template<int TM>
__global__ __launch_bounds__(256) void gemm_abt(const float* __restrict__ A, int lda,
                                                const float* __restrict__ Bm, int ldb,
                                                const float* __restrict__ bias,
                                                float* __restrict__ C, int ldc, int K){
    constexpr int RPT = TM / 16;
    __shared__ float As[16][TM + 4];
    __shared__ float Bs[16][64 + 4];
    int m0 = blockIdx.x * TM, n0 = blockIdx.y * 64;
    int tid = threadIdx.x;
    int lk = tid & 15, lr = tid >> 4;
    int tx = tid & 15, ty = tid >> 4;
    float c[RPT][4] = {};
    for (int k0 = 0; k0 < K; k0 += 16){
#pragma unroll
        for (int i = 0; i < RPT; ++i)
            As[lk][lr*RPT + i] = A[(size_t)(m0 + lr*RPT + i)*lda + k0 + lk];
#pragma unroll
        for (int i = 0; i < 4; ++i)
            Bs[lk][lr*4 + i] = Bm[(size_t)(n0 + lr*4 + i)*ldb + k0 + lk];
        __syncthreads();
#pragma unroll
        for (int k = 0; k < 16; ++k){
            float b4[4];
            *(float4*)b4 = *(const float4*)&Bs[k][tx*4];
#pragma unroll
            for (int i = 0; i < RPT; ++i){
                float a = As[k][ty*RPT + i];
#pragma unroll
                for (int j = 0; j < 4; ++j) c[i][j] += a * b4[j];
            }
        }
        __syncthreads();
    }
#pragma unroll
    for (int j = 0; j < 4; ++j){
        float bb = bias ? bias[n0 + tx*4 + j] : 0.f;
#pragma unroll
        for (int i = 0; i < RPT; ++i)
            C[(size_t)(m0 + ty*RPT + i)*ldc + n0 + tx*4 + j] = c[i][j] + bb;
    }
}

// ---------------- one-time transforms ----------------
__global__ __launch_bounds__(256) void split_mat(const float* __restrict__ src,
                                                 u16* __restrict__ hi, u16* __restrict__ lo){
    int idx = (blockIdx.x * 256 + threadIdx.x) * 4;
    float4 v = *(const float4*)&src[idx];
    ushort4v h, l; split_f4(v, h, l);
    *(ushort4v*)&hi[idx] = h;
    *(ushort4v*)&lo[idx] = l;
}

__global__ __launch_bounds__(256) void split_rows1024(const float* __restrict__ src,
                                                      u16* __restrict__ hi, u16* __restrict__ lo){
    int id = (blockIdx.x * 256 + threadIdx.x) * 4;
    int r = id >> 10, c = id & 1023;
    float4 v = *(const float4*)&src[(size_t)r*1536 + c];
    ushort4v h, l; split_f4(v, h, l);
    *(ushort4v*)&hi[id] = h;
    *(ushort4v*)&lo[id] = l;
}

__global__ __launch_bounds__(256) void wo_split(const float* __restrict__ Wo,
                                                u16* __restrict__ Thi, u16* __restrict__ Tlo){
    __shared__ float T[64][65];
    int k0 = blockIdx.x * 64, n0 = blockIdx.y * 64;
    int tid = threadIdx.x;
#pragma unroll
    for (int i = 0; i < 16; ++i){
        int idx = tid + i*256;
        int kk = idx >> 6, nn = idx & 63;
        T[kk][nn] = Wo[(size_t)(k0+kk)*4096 + n0+nn];
    }
    __syncthreads();
#pragma unroll
    for (int i = 0; i < 16; ++i){
        int idx = tid + i*256;
        int nn = idx >> 6, kk = idx & 63;
        float v = T[kk][nn];
        u16 hi = bf16_rne(v);
        u16 lo = bf16_rne(v - __uint_as_float(((unsigned)hi) << 16));
        size_t o = (size_t)(n0+nn)*512 + k0+kk;
        Thi[o] = hi; Tlo[o] = lo;
    }
}

__global__ __launch_bounds__(256) void zero_u32(unsigned* __restrict__ p, int n){
    int i = blockIdx.x * 256 + threadIdx.x;
    if (i < n) p[i] = 0u;
}

// ---------------- Eproj: emb(4096x1024) @ WihL^T(1536x1024), u16 inputs ----------------
__global__ __launch_bounds__(256) void eproj_u16(const u16* __restrict__ Ahi, const u16* __restrict__ Alo,
                                                 const u16* __restrict__ Bhi, const u16* __restrict__ Blo,
                                                 float* __restrict__ C){
    __shared__ u16 Ah[64][40], Al[64][40], Bh[64][40], Bl[64][40];
    int n0 = blockIdx.x * 64, m0 = blockIdx.y * 64;
    int tid = threadIdx.x, lane = tid & 63, wid = tid >> 6;
    int wm = (wid & 1) * 32, wn = (wid >> 1) * 32;
    int l15 = lane & 15, lk = (lane >> 4) * 8;
    f32x4 acc[2][2] = {};
    short8v ra[2], rb[2];
#pragma unroll
    for (int j = 0; j < 2; ++j){
        int c = j*256 + tid;
        int half = c >> 8, i = c & 255, row = i >> 2, k8 = (i & 3)*8;
        ra[j] = *(const short8v*)&(half ? Alo : Ahi)[(size_t)(m0+row)*1024 + k8];
        rb[j] = *(const short8v*)&(half ? Blo : Bhi)[(size_t)(n0+row)*1024 + k8];
    }
    for (int k0 = 0; k0 < 1024; k0 += 32){
        __syncthreads();
#pragma unroll
        for (int j = 0; j < 2; ++j){
            int c = j*256 + tid;
            int half = c >> 8, i = c & 255, row = i >> 2, k8 = (i & 3)*8;
            if (half){ *(short8v*)&Al[row][k8] = ra[j]; *(short8v*)&Bl[row][k8] = rb[j]; }
            else     { *(short8v*)&Ah[row][k8] = ra[j]; *(short8v*)&Bh[row][k8] = rb[j]; }
        }
        __syncthreads();
        if (k0 + 32 < 1024){
#pragma unroll
            for (int j = 0; j < 2; ++j){
                int c = j*256 + tid;
                int half = c >> 8, i = c & 255, row = i >> 2, k8 = (i & 3)*8;
                ra[j] = *(const short8v*)&(half ? Alo : Ahi)[(size_t)(m0+row)*1024 + k0+32 + k8];
                rb[j] = *(const short8v*)&(half ? Blo : Bhi)[(size_t)(n0+row)*1024 + k0+32 + k8];
            }
        }
        short8v ah0 = *(const short8v*)&Ah[wm +  0 + l15][lk];
        short8v ah1 = *(const short8v*)&Ah[wm + 16 + l15][lk];
        short8v al0 = *(const short8v*)&Al[wm +  0 + l15][lk];
        short8v al1 = *(const short8v*)&Al[wm + 16 + l15][lk];
        short8v bh0 = *(const short8v*)&Bh[wn +  0 + l15][lk];
        short8v bh1 = *(const short8v*)&Bh[wn + 16 + l15][lk];
        short8v bl0 = *(const short8v*)&Bl[wn +  0 + l15][lk];
        short8v bl1 = *(const short8v*)&Bl[wn + 16 + l15][lk];
        MFMA3(acc[0][0], ah0, al0, bh0, bl0);
        MFMA3(acc[0][1], ah0, al0, bh1, bl1);
        MFMA3(acc[1][0], ah1, al1, bh0, bl0);
        MFMA3(acc[1][1], ah1, al1, bh1, bl1);
    }
    int col0 = n0 + wn + l15;
    int rg = lane >> 4;
#pragma unroll
    for (int mf = 0; mf < 2; ++mf)
#pragma unroll
        for (int r = 0; r < 4; ++r){
            int row = m0 + wm + mf*16 + rg*4 + r;
            C[(size_t)row*1536 + col0]      = acc[mf][0][r];
            C[(size_t)row*1536 + col0 + 16] = acc[mf][1][r];
        }
}

// ---------------- per-step kernels (no LDS, no barriers) ----------------

// GRU pointwise: hn = GRU(gh, Eproj[w], gictx, h); writes hn f32 + bf16 splits.
// Also decodes w(t-1) from P and writes preds[:, t-1]. grid 128 x 256 thr (2 rows/block).
__global__ __launch_bounds__(256) void gru_pointwise(
    const float* __restrict__ gh, const float* __restrict__ Eproj,
    const float* __restrict__ gictx, const float* __restrict__ bhh,
    const float* __restrict__ hprev, float* __restrict__ hnext,
    u16* __restrict__ Sh, u16* __restrict__ Sl,
    const unsigned long long* __restrict__ Pprev,
    float* __restrict__ preds, int t)
{
    int tid = threadIdx.x;
    int row = blockIdx.x * 2 + (tid >> 7);
    int jj = (tid & 127) * 4;
    int w = 1;
    if (t > 0){
        w = 4095 - (int)(Pprev[row] & 0xFFFFFFFFull);
        if (w < 0) w = 0; if (w > 4095) w = 4095;
        if (jj == 0) preds[row*NSTEP + (t-1)] = (float)w;
    }
    const float* gr = gh + (size_t)row * 1536;
    const float* ep = Eproj + (size_t)w * 1536;
    const float* gc = gictx + (size_t)row * 1536;
    float4 g0 = *(const float4*)&gr[jj];
    float4 g1 = *(const float4*)&gr[512 + jj];
    float4 g2 = *(const float4*)&gr[1024 + jj];
    float4 e0 = *(const float4*)&ep[jj];
    float4 e1 = *(const float4*)&ep[512 + jj];
    float4 e2 = *(const float4*)&ep[1024 + jj];
    float4 c0 = *(const float4*)&gc[jj];
    float4 c1 = *(const float4*)&gc[512 + jj];
    float4 c2 = *(const float4*)&gc[1024 + jj];
    float4 b0 = *(const float4*)&bhh[jj];
    float4 b1 = *(const float4*)&bhh[512 + jj];
    float4 b2 = *(const float4*)&bhh[1024 + jj];
    float4 ho = *(const float4*)&hprev[(size_t)row*512 + jj];
    const float* G0 = (const float*)&g0; const float* G1 = (const float*)&g1;
    const float* G2 = (const float*)&g2;
    const float* E0 = (const float*)&e0; const float* E1 = (const float*)&e1;
    const float* E2 = (const float*)&e2;
    const float* C0 = (const float*)&c0; const float* C1 = (const float*)&c1;
    const float* C2 = (const float*)&c2;
    const float* B0 = (const float*)&b0; const float* B1 = (const float*)&b1;
    const float* B2 = (const float*)&b2;
    const float* HO = (const float*)&ho;
    float4 res;
    float* R = (float*)&res;
#pragma unroll
    for (int i = 0; i < 4; ++i){
        float gir = E0[i] + C0[i] + G0[i] + B0[i];
        float giz = E1[i] + C1[i] + G1[i] + B1[i];
        float gin = E2[i] + C2[i];
        float rr = 1.f / (1.f + expf(-gir));
        float zz = 1.f / (1.f + expf(-giz));
        float nn = tanhf(gin + rr * (G2[i] + B2[i]));
        R[i] = (1.f - zz)*nn + zz*HO[i];
    }
    size_t o = (size_t)row*512 + jj;
    *(float4*)&hnext[o] = res;
    ushort4v h4, l4; split_f4(res, h4, l4);
    *(ushort4v*)&Sh[o] = h4;
    *(ushort4v*)&Sl[o] = l4;
}

// Fused logits(t) + gh(t+1): direct-global fragment loads, no LDS/barriers.
// Wave tile 64 rows x 16 cols; block = 4 waves = 64x64 tile.
// grid (4 m-tiles, n_logits + 24): nt < n_logits -> logits(+argmax); else gh col-tile.
__global__ __launch_bounds__(256) void bigmm(
    const u16* __restrict__ Ah, const u16* __restrict__ Al,
    const u16* __restrict__ WoHi, const u16* __restrict__ WoLo,
    const u16* __restrict__ WhhHi, const u16* __restrict__ WhhLo,
    const float* __restrict__ bo,
    float* __restrict__ logits,             // out + t*V_, row stride NSTEP*V_
    unsigned long long* __restrict__ P,
    float* __restrict__ gh,
    int n_logits)
{
    int m0 = blockIdx.x * 64;
    int nt = blockIdx.y;
    bool isL = nt < n_logits;
    int wid = threadIdx.x >> 6, lane = threadIdx.x & 63;
    int l15 = lane & 15, hk8 = (lane >> 4) * 8, rg = lane >> 4;
    int col0 = (isL ? nt : nt - n_logits) * 64 + wid * 16;
    const u16* Bhp = isL ? WoHi : WhhHi;
    const u16* Blp = isL ? WoLo : WhhLo;
    const size_t aoff = (size_t)(m0 + l15) * 512 + hk8;
    const size_t boff = (size_t)(col0 + l15) * 512 + hk8;
    f32x4 acc[4] = {};
    short8v ah[4], al[4], bh, bl;
#pragma unroll
    for (int f = 0; f < 4; ++f){
        ah[f] = *(const short8v*)&Ah[aoff + (size_t)f*16*512];
        al[f] = *(const short8v*)&Al[aoff + (size_t)f*16*512];
    }
    bh = *(const short8v*)&Bhp[boff];
    bl = *(const short8v*)&Blp[boff];
    for (int k0 = 0; k0 < 512; k0 += 32){
        short8v nah[4], nal[4], nbh, nbl;
        if (k0 + 32 < 512){
#pragma unroll
            for (int f = 0; f < 4; ++f){
                nah[f] = *(const short8v*)&Ah[aoff + (size_t)f*16*512 + k0 + 32];
                nal[f] = *(const short8v*)&Al[aoff + (size_t)f*16*512 + k0 + 32];
            }
            nbh = *(const short8v*)&Bhp[boff + k0 + 32];
            nbl = *(const short8v*)&Blp[boff + k0 + 32];
        }
#pragma unroll
        for (int f = 0; f < 4; ++f) MFMA3(acc[f], ah[f], al[f], bh, bl);
        if (k0 + 32 < 512){
#pragma unroll
            for (int f = 0; f < 4; ++f){ ah[f] = nah[f]; al[f] = nal[f]; }
            bh = nbh; bl = nbl;
        }
    }
    int col = col0 + l15;
    if (isL){
        float bov = bo[col];
#pragma unroll
        for (int f = 0; f < 4; ++f){
#pragma unroll
            for (int r = 0; r < 4; ++r){
                int row = m0 + f*16 + rg*4 + r;
                float v = acc[f][r] + bov;
                logits[(size_t)row * (NSTEP*(size_t)V_) + col] = v;
                unsigned long long key = ((unsigned long long)fkey(v) << 32) | (unsigned)(4095 - col);
#pragma unroll
                for (int off = 1; off < 16; off <<= 1){
                    unsigned long long o = __shfl_xor(key, off);
                    if (o > key) key = o;
                }
                if (l15 == 0) atomicMax(&P[row], key);
            }
        }
    } else {
#pragma unroll
        for (int f = 0; f < 4; ++f)
#pragma unroll
            for (int r = 0; r < 4; ++r)
                gh[(size_t)(m0 + f*16 + rg*4 + r)*1536 + col] = acc[f][r];
    }
}

__global__ __launch_bounds__(256) void final_pred(const unsigned long long* __restrict__ P,
                                                  float* __restrict__ preds){
    int b = threadIdx.x;
    int w = 4095 - (int)(P[b] & 0xFFFFFFFFull);
    if (w < 0) w = 0; if (w > 4095) w = 4095;
    preds[b*NSTEP + (NSTEP-1)] = (float)w;
}

extern "C" void kernel_launch(void* const* d_in, const int* in_sizes, int n_in,
                              void* d_out, int out_size, void* d_ws, size_t ws_size,
                              hipStream_t stream){
    const float* elhs = (const float*)d_in[0];
    const float* enc  = (const float*)d_in[1];
    const float* emb  = (const float*)d_in[3];
    const float* W1   = (const float*)d_in[4];
    const float* W2   = (const float*)d_in[6];
    const float* W3   = (const float*)d_in[8];
    const float* W4   = (const float*)d_in[10];
    const float* Ww   = (const float*)d_in[12];
    const float* Wih  = (const float*)d_in[13];
    const float* bih  = (const float*)d_in[14];
    const float* Whh  = (const float*)d_in[15];
    const float* bhh  = (const float*)d_in[16];
    const float* Wo   = (const float*)d_in[17];
    const float* bo   = (const float*)d_in[18];

    float* out = (float*)d_out;
    float* preds = out + (size_t)B_ * NSTEP * V_;

    float* ws = (float*)d_ws;
    float* Eproj  = ws;  ws += (size_t)V_ * 1536;
    float* gictx  = ws;  ws += (size_t)B_ * 1536;
    float* ctx    = ws;  ws += B_ * H_;
    float* scores = ws;  ws += B_ * S_;
    float* t1     = ws;  ws += 512;
    float* t2     = ws;  ws += 512;
    float* weff   = ws;  ws += 512;
    float* Hf     = ws;  ws += 2 * B_ * H_;
    float* ghbuf  = ws;  ws += B_ * 1536;
    u16* WoT_hi = (u16*)ws;  ws += (size_t)V_ * 512 / 2;
    u16* WoT_lo = (u16*)ws;  ws += (size_t)V_ * 512 / 2;
    u16* WhhHi  = (u16*)ws;  ws += 1536 * 512 / 2;
    u16* WhhLo  = (u16*)ws;  ws += 1536 * 512 / 2;
    u16* Sh     = (u16*)ws;  ws += B_ * H_ / 2;
    u16* Sl     = (u16*)ws;  ws += B_ * H_ / 2;
    unsigned long long* P = (unsigned long long*)ws;   // 27*256 u64

    // big one-time splits parked in d_out head (consumed by eproj before logits writes)
    u16* EmbHi  = (u16*)d_out;                       // 4096x1024
    u16* EmbLo  = EmbHi + (size_t)V_*1024;
    u16* WihLHi = EmbLo + (size_t)V_*1024;           // 1536x1024 compact
    u16* WihLLo = WihLHi + (size_t)1536*1024;

    // one-time transforms
    split_mat<<<1536*512/(4*256), 256, 0, stream>>>(Whh, WhhHi, WhhLo);
    { dim3 g(512/64, V_/64); wo_split<<<g, 256, 0, stream>>>(Wo, WoT_hi, WoT_lo); }
    split_mat<<<V_*1024/(4*256), 256, 0, stream>>>(emb, EmbHi, EmbLo);
    split_rows1024<<<1536*1024/(4*256), 256, 0, stream>>>(Wih, WihLHi, WihLLo);
    split_mat<<<B_*H_/(4*256), 256, 0, stream>>>(elhs, Sh, Sl);     // h0 splits
    zero_u32<<<(NSTEP*256*2 + 255)/256, 256, 0, stream>>>((unsigned*)P, NSTEP*256*2);

    // front: collapsed attention (h-independent), context, gi_ctx, Eproj
    matvec512<<<512, 64, 0, stream>>>(W4, Ww, t1);
    matvec512<<<512, 64, 0, stream>>>(W3, t1, t2);
    matvec512<<<512, 64, 0, stream>>>(W2, t2, t1);
    matvec512<<<512, 64, 0, stream>>>(W1, t1, weff);
    score_kernel<<<(B_*S_)/4, 256, 0, stream>>>(enc, weff, scores);
    softmax_ctx<<<B_, 512, 0, stream>>>(enc, scores, ctx);
    { dim3 g(B_/32, 1536/64);
      gemm_abt<32><<<g, 256, 0, stream>>>(ctx, 512, Wih + 1024, 1536, bih, gictx, 1536, 512); }
    { dim3 g(1536/64, V_/64);
      eproj_u16<<<g, 256, 0, stream>>>(EmbHi, EmbLo, WihLHi, WihLLo, Eproj); }

    // gh_0 = h0 @ Whh^T  (gh-only bigmm)
    { dim3 g(4, 24);
      bigmm<<<g, 256, 0, stream>>>(Sh, Sl, WoT_hi, WoT_lo, WhhHi, WhhLo, bo,
                                   out, P, ghbuf, 0); }

    for (int t = 0; t < NSTEP; ++t){
        const float* hr = (t == 0) ? elhs : (Hf + (size_t)((t-1) & 1) * (B_*H_));
        float* hw = Hf + (size_t)(t & 1) * (B_*H_);
        gru_pointwise<<<128, 256, 0, stream>>>(ghbuf, Eproj, gictx, bhh, hr, hw,
                                               Sh, Sl, P + (size_t)(t-1)*256, preds, t);
        dim3 g(4, 64 + 24);
        bigmm<<<g, 256, 0, stream>>>(Sh, Sl, WoT_hi, WoT_lo, WhhHi, WhhLo, bo,
                                     out + (size_t)t * V_, P + (size_t)t*256, ghbuf, 64);
    }
    final_pred<<<1, 256, 0, stream>>>(P + (size_t)(NSTEP-1)*256, preds);
}

// Round 6
// 778.307 us; speedup vs baseline: 3.1396x; 2.2807x over previous
//
#include <hip/hip_runtime.h>

#define B_ 256
#define S_ 80
#define H_ 512
#define V_ 4096
#define NSTEP 27

typedef unsigned short u16;
typedef __attribute__((ext_vector_type(8))) short short8v;
typedef __attribute__((ext_vector_type(4))) float f32x4;
typedef __attribute__((ext_vector_type(4))) unsigned short ushort4v;

#define MFMA_(a,b,c) __builtin_amdgcn_mfma_f32_16x16x32_bf16(a,b,c,0,0,0)
#define MFMA3(acc, ah, al, bh, bl) do{ acc = MFMA_(ah,bh,acc); acc = MFMA_(ah,bl,acc); acc = MFMA_(al,bh,acc);}while(0)

__device__ __forceinline__ unsigned fkey(float v){
    unsigned u = __float_as_uint(v);
    return (u & 0x80000000u) ? ~u : (u | 0x80000000u);
}
__device__ __forceinline__ u16 bf16_rne(float f){
    unsigned u = __float_as_uint(f);
    return (u16)((u + 0x7FFFu + ((u >> 16) & 1u)) >> 16);
}
__device__ __forceinline__ void split_f4(float4 v, ushort4v& hi, ushort4v& lo){
    float arr[4] = {v.x, v.y, v.z, v.w};
    ushort4v h, l;
#pragma unroll
    for (int i = 0; i < 4; ++i){
        u16 hb = bf16_rne(arr[i]);
        h[i] = hb;
        l[i] = bf16_rne(arr[i] - __uint_as_float(((unsigned)hb) << 16));
    }
    hi = h; lo = l;
}

// ---------------- front ----------------
__global__ __launch_bounds__(64) void matvec512(const float* __restrict__ W,
                                                const float* __restrict__ v,
                                                float* __restrict__ out){
    int row = blockIdx.x, lane = threadIdx.x;
    const float* wr = W + row * 512;
    float s = 0.f;
#pragma unroll
    for (int i = 0; i < 8; ++i) s += wr[lane + 64*i] * v[lane + 64*i];
#pragma unroll
    for (int off = 32; off; off >>= 1) s += __shfl_xor(s, off);
    if (lane == 0) out[row] = s;
}

__global__ __launch_bounds__(256) void score_kernel(const float* __restrict__ enc,
                                                    const float* __restrict__ weff,
                                                    float* __restrict__ scores){
    int wv = threadIdx.x >> 6, lane = threadIdx.x & 63;
    int p = blockIdx.x * 4 + wv;
    const float* e = enc + (size_t)p * 512;
    float s = 0.f;
#pragma unroll
    for (int i = 0; i < 8; ++i) s += e[lane + 64*i] * weff[lane + 64*i];
#pragma unroll
    for (int off = 32; off; off >>= 1) s += __shfl_xor(s, off);
    if (lane == 0) scores[p] = s;
}

__global__ __launch_bounds__(512) void softmax_ctx(const float* __restrict__ enc,
                                                   const float* __restrict__ scores,
                                                   float* __restrict__ ctx){
    __shared__ float att[S_];
    int b = blockIdx.x, tid = threadIdx.x;
    if (tid < S_) att[tid] = scores[b*S_ + tid];
    __syncthreads();
    if (tid == 0){
        float mx = att[0];
        for (int s = 1; s < S_; ++s) mx = fmaxf(mx, att[s]);
        float sum = 0.f;
        for (int s = 0; s < S_; ++s){ float e = expf(att[s] - mx); att[s] = e; sum += e; }
        float inv = 1.f / sum;
        for (int s = 0; s < S_; ++s) att[s] *= inv;
    }
    __syncthreads();
    float a = 0.f;
    const float* eb = enc + (size_t)b * (S_*H_);
    for (int s = 0; s < S_; ++s) a += att[s] * eb[s*H_ + tid];
    ctx[b*H_ + tid] = a;
}

template<int TM>
__global__ __launch_bounds__(256) void gemm_abt(const float* __restrict__ A, int lda,
                                                const float* __restrict__ Bm, int ldb,
                                                const float* __restrict__ bias,
                                                float* __restrict__ C, int ldc, int K){
    constexpr int RPT = TM / 16;
    __shared__ float As[16][TM + 4];
    __shared__ float Bs[16][64 + 4];
    int m0 = blockIdx.x * TM, n0 = blockIdx.y * 64;
    int tid = threadIdx.x;
    int lk = tid & 15, lr = tid >> 4;
    int tx = tid & 15, ty = tid >> 4;
    float c[RPT][4] = {};
    for (int k0 = 0; k0 < K; k0 += 16){
#pragma unroll
        for (int i = 0; i < RPT; ++i)
            As[lk][lr*RPT + i] = A[(size_t)(m0 + lr*RPT + i)*lda + k0 + lk];
#pragma unroll
        for (int i = 0; i < 4; ++i)
            Bs[lk][lr*4 + i] = Bm[(size_t)(n0 + lr*4 + i)*ldb + k0 + lk];
        __syncthreads();
#pragma unroll
        for (int k = 0; k < 16; ++k){
            float b4[4];
            *(float4*)b4 = *(const float4*)&Bs[k][tx*4];
#pragma unroll
            for (int i = 0; i < RPT; ++i){
                float a = As[k][ty*RPT + i];
#pragma unroll
                for (int j = 0; j < 4; ++j) c[i][j] += a * b4[j];
            }
        }
        __syncthreads();
    }
#pragma unroll
    for (int j = 0; j < 4; ++j){
        float bb = bias ? bias[n0 + tx*4 + j] : 0.f;
#pragma unroll
        for (int i = 0; i < RPT; ++i)
            C[(size_t)(m0 + ty*RPT + i)*ldc + n0 + tx*4 + j] = c[i][j] + bb;
    }
}

// ---------------- one-time transforms fused into a single kernel ----------------
// block ranges: [0,768) Whh split | [768,1280) wo transpose+split | [1280,5376) emb
// | [5376,6912) WihL | [6912,7040) h0 | [7040,7054) zero P
__global__ __launch_bounds__(256) void prep_all(
    const float* __restrict__ Whh, const float* __restrict__ Wo,
    const float* __restrict__ emb, const float* __restrict__ Wih,
    const float* __restrict__ elhs,
    u16* __restrict__ WhhHi, u16* __restrict__ WhhLo,
    u16* __restrict__ WoThi, u16* __restrict__ WoTlo,
    u16* __restrict__ EmbHi, u16* __restrict__ EmbLo,
    u16* __restrict__ WihLHi, u16* __restrict__ WihLLo,
    u16* __restrict__ Sh, u16* __restrict__ Sl,
    unsigned* __restrict__ zp, int nz)
{
    __shared__ float T[64][65];
    int b = blockIdx.x, tid = threadIdx.x;
    if (b < 768){
        int idx = (b*256 + tid)*4;
        float4 v = *(const float4*)&Whh[idx];
        ushort4v h,l; split_f4(v,h,l);
        *(ushort4v*)&WhhHi[idx]=h; *(ushort4v*)&WhhLo[idx]=l;
    } else if (b < 1280){
        int lb = b - 768;
        int k0 = (lb & 7)*64, n0 = (lb >> 3)*64;
#pragma unroll
        for (int i = 0; i < 16; ++i){
            int idx = tid + i*256;
            int kk = idx >> 6, nn = idx & 63;
            T[kk][nn] = Wo[(size_t)(k0+kk)*4096 + n0+nn];
        }
        __syncthreads();
#pragma unroll
        for (int i = 0; i < 16; ++i){
            int idx = tid + i*256;
            int nn = idx >> 6, kk = idx & 63;
            float v = T[kk][nn];
            u16 hi = bf16_rne(v);
            u16 lo = bf16_rne(v - __uint_as_float(((unsigned)hi) << 16));
            size_t o = (size_t)(n0+nn)*512 + k0+kk;
            WoThi[o] = hi; WoTlo[o] = lo;
        }
    } else if (b < 5376){
        int idx = ((b-1280)*256 + tid)*4;
        float4 v = *(const float4*)&emb[idx];
        ushort4v h,l; split_f4(v,h,l);
        *(ushort4v*)&EmbHi[idx]=h; *(ushort4v*)&EmbLo[idx]=l;
    } else if (b < 6912){
        int id = ((b-5376)*256 + tid)*4;
        int r = id >> 10, c = id & 1023;
        float4 v = *(const float4*)&Wih[(size_t)r*1536 + c];
        ushort4v h,l; split_f4(v,h,l);
        *(ushort4v*)&WihLHi[id]=h; *(ushort4v*)&WihLLo[id]=l;
    } else if (b < 7040){
        int idx = ((b-6912)*256 + tid)*4;
        float4 v = *(const float4*)&elhs[idx];
        ushort4v h,l; split_f4(v,h,l);
        *(ushort4v*)&Sh[idx]=h; *(ushort4v*)&Sl[idx]=l;
    } else {
        int i = ((b-7040)*256 + tid)*4;
        if (i < nz){ zp[i]=0u; zp[i+1]=0u; zp[i+2]=0u; zp[i+3]=0u; }
    }
}

// ---------------- Eproj: emb(4096x1024) @ WihL^T(1536x1024), u16 inputs ----------------
__global__ __launch_bounds__(256) void eproj_u16(const u16* __restrict__ Ahi, const u16* __restrict__ Alo,
                                                 const u16* __restrict__ Bhi, const u16* __restrict__ Blo,
                                                 float* __restrict__ C){
    __shared__ u16 Ah[64][40], Al[64][40], Bh[64][40], Bl[64][40];
    int n0 = blockIdx.x * 64, m0 = blockIdx.y * 64;
    int tid = threadIdx.x, lane = tid & 63, wid = tid >> 6;
    int wm = (wid & 1) * 32, wn = (wid >> 1) * 32;
    int l15 = lane & 15, lk = (lane >> 4) * 8;
    f32x4 acc[2][2] = {};
    short8v ra[2], rb[2];
#pragma unroll
    for (int j = 0; j < 2; ++j){
        int c = j*256 + tid;
        int half = c >> 8, i = c & 255, row = i >> 2, k8 = (i & 3)*8;
        ra[j] = *(const short8v*)&(half ? Alo : Ahi)[(size_t)(m0+row)*1024 + k8];
        rb[j] = *(const short8v*)&(half ? Blo : Bhi)[(size_t)(n0+row)*1024 + k8];
    }
    for (int k0 = 0; k0 < 1024; k0 += 32){
        __syncthreads();
#pragma unroll
        for (int j = 0; j < 2; ++j){
            int c = j*256 + tid;
            int half = c >> 8, i = c & 255, row = i >> 2, k8 = (i & 3)*8;
            if (half){ *(short8v*)&Al[row][k8] = ra[j]; *(short8v*)&Bl[row][k8] = rb[j]; }
            else     { *(short8v*)&Ah[row][k8] = ra[j]; *(short8v*)&Bh[row][k8] = rb[j]; }
        }
        __syncthreads();
        if (k0 + 32 < 1024){
#pragma unroll
            for (int j = 0; j < 2; ++j){
                int c = j*256 + tid;
                int half = c >> 8, i = c & 255, row = i >> 2, k8 = (i & 3)*8;
                ra[j] = *(const short8v*)&(half ? Alo : Ahi)[(size_t)(m0+row)*1024 + k0+32 + k8];
                rb[j] = *(const short8v*)&(half ? Blo : Bhi)[(size_t)(n0+row)*1024 + k0+32 + k8];
            }
        }
        short8v ah0 = *(const short8v*)&Ah[wm +  0 + l15][lk];
        short8v ah1 = *(const short8v*)&Ah[wm + 16 + l15][lk];
        short8v al0 = *(const short8v*)&Al[wm +  0 + l15][lk];
        short8v al1 = *(const short8v*)&Al[wm + 16 + l15][lk];
        short8v bh0 = *(const short8v*)&Bh[wn +  0 + l15][lk];
        short8v bh1 = *(const short8v*)&Bh[wn + 16 + l15][lk];
        short8v bl0 = *(const short8v*)&Bl[wn +  0 + l15][lk];
        short8v bl1 = *(const short8v*)&Bl[wn + 16 + l15][lk];
        MFMA3(acc[0][0], ah0, al0, bh0, bl0);
        MFMA3(acc[0][1], ah0, al0, bh1, bl1);
        MFMA3(acc[1][0], ah1, al1, bh0, bl0);
        MFMA3(acc[1][1], ah1, al1, bh1, bl1);
    }
    int col0 = n0 + wn + l15;
    int rg = lane >> 4;
#pragma unroll
    for (int mf = 0; mf < 2; ++mf)
#pragma unroll
        for (int r = 0; r < 4; ++r){
            int row = m0 + wm + mf*16 + rg*4 + r;
            C[(size_t)row*1536 + col0]      = acc[mf][0][r];
            C[(size_t)row*1536 + col0 + 16] = acc[mf][1][r];
        }
}

// ---------------- per-step kernels ----------------

// GRU pointwise (proven): hn = GRU(gh, Eproj[w], gictx, h); writes hn f32 + bf16 splits.
__global__ __launch_bounds__(256) void gru_pointwise(
    const float* __restrict__ gh, const float* __restrict__ Eproj,
    const float* __restrict__ gictx, const float* __restrict__ bhh,
    const float* __restrict__ hprev, float* __restrict__ hnext,
    u16* __restrict__ Sh, u16* __restrict__ Sl,
    const unsigned long long* __restrict__ Pprev,
    float* __restrict__ preds, int t)
{
    int tid = threadIdx.x;
    int row = blockIdx.x * 2 + (tid >> 7);
    int jj = (tid & 127) * 4;
    int w = 1;
    if (t > 0){
        w = 4095 - (int)(Pprev[row] & 0xFFFFFFFFull);
        if (w < 0) w = 0; if (w > 4095) w = 4095;
        if (jj == 0) preds[row*NSTEP + (t-1)] = (float)w;
    }
    const float* gr = gh + (size_t)row * 1536;
    const float* ep = Eproj + (size_t)w * 1536;
    const float* gc = gictx + (size_t)row * 1536;
    float4 g0 = *(const float4*)&gr[jj];
    float4 g1 = *(const float4*)&gr[512 + jj];
    float4 g2 = *(const float4*)&gr[1024 + jj];
    float4 e0 = *(const float4*)&ep[jj];
    float4 e1 = *(const float4*)&ep[512 + jj];
    float4 e2 = *(const float4*)&ep[1024 + jj];
    float4 c0 = *(const float4*)&gc[jj];
    float4 c1 = *(const float4*)&gc[512 + jj];
    float4 c2 = *(const float4*)&gc[1024 + jj];
    float4 b0 = *(const float4*)&bhh[jj];
    float4 b1 = *(const float4*)&bhh[512 + jj];
    float4 b2 = *(const float4*)&bhh[1024 + jj];
    float4 ho = *(const float4*)&hprev[(size_t)row*512 + jj];
    const float* G0 = (const float*)&g0; const float* G1 = (const float*)&g1;
    const float* G2 = (const float*)&g2;
    const float* E0 = (const float*)&e0; const float* E1 = (const float*)&e1;
    const float* E2 = (const float*)&e2;
    const float* C0 = (const float*)&c0; const float* C1 = (const float*)&c1;
    const float* C2 = (const float*)&c2;
    const float* B0 = (const float*)&b0; const float* B1 = (const float*)&b1;
    const float* B2 = (const float*)&b2;
    const float* HO = (const float*)&ho;
    float4 res;
    float* R = (float*)&res;
#pragma unroll
    for (int i = 0; i < 4; ++i){
        float gir = E0[i] + C0[i] + G0[i] + B0[i];
        float giz = E1[i] + C1[i] + G1[i] + B1[i];
        float gin = E2[i] + C2[i];
        float rr = 1.f / (1.f + expf(-gir));
        float zz = 1.f / (1.f + expf(-giz));
        float nn = tanhf(gin + rr * (G2[i] + B2[i]));
        R[i] = (1.f - zz)*nn + zz*HO[i];
    }
    size_t o = (size_t)row*512 + jj;
    *(float4*)&hnext[o] = res;
    ushort4v h4, l4; split_f4(res, h4, l4);
    *(ushort4v*)&Sh[o] = h4;
    *(ushort4v*)&Sl[o] = l4;
}

// Fused logits(t)+argmax and gh(t+1), LDS-staged split-bf16 MFMA.
// Block tile 64 rows x 128 cols; 4 waves as 2(row)x2(col); per wave 32x64.
// grid (4, n_logits + 12); nt < n_logits -> logits cols (128-wide), else gh cols.
__global__ __launch_bounds__(256) void step_mm(
    const u16* __restrict__ Ahg, const u16* __restrict__ Alg,
    const u16* __restrict__ WoHi, const u16* __restrict__ WoLo,
    const u16* __restrict__ WhhHi, const u16* __restrict__ WhhLo,
    const float* __restrict__ bo,
    float* __restrict__ logits, unsigned long long* __restrict__ P,
    float* __restrict__ gh, int n_logits)
{
    __shared__ u16 Ah[64][40], Al[64][40], Bh[128][40], Bl[128][40];
    int m0 = blockIdx.x * 64;
    int nt = blockIdx.y;
    bool isL = nt < n_logits;
    int nbase = (isL ? nt : nt - n_logits) * 128;
    const u16* Bhg = isL ? WoHi : WhhHi;
    const u16* Blg = isL ? WoLo : WhhLo;
    int tid = threadIdx.x, lane = tid & 63, wid = tid >> 6;
    int wy = wid & 1, wx = wid >> 1;
    int l15 = lane & 15, rg = lane >> 4, lk = rg * 8;
    // staging: A = 64x32 shorts per split (256 chunks of 8); B = 128x32 (512 chunks)
    int ar = tid >> 2, ak8 = (tid & 3) * 8;
    const u16* agH = Ahg + (size_t)(m0 + ar)*512 + ak8;
    const u16* agL = Alg + (size_t)(m0 + ar)*512 + ak8;
    const u16* bgH0 = Bhg + (size_t)(nbase + ar)*512 + ak8;
    const u16* bgL0 = Blg + (size_t)(nbase + ar)*512 + ak8;
    const u16* bgH1 = bgH0 + (size_t)64*512;
    const u16* bgL1 = bgL0 + (size_t)64*512;
    f32x4 acc[2][4] = {};
    short8v ra_h = *(const short8v*)agH;
    short8v ra_l = *(const short8v*)agL;
    short8v rb_h0 = *(const short8v*)bgH0;
    short8v rb_l0 = *(const short8v*)bgL0;
    short8v rb_h1 = *(const short8v*)bgH1;
    short8v rb_l1 = *(const short8v*)bgL1;
    for (int k0 = 0; k0 < 512; k0 += 32){
        __syncthreads();
        *(short8v*)&Ah[ar][ak8] = ra_h;
        *(short8v*)&Al[ar][ak8] = ra_l;
        *(short8v*)&Bh[ar][ak8] = rb_h0;
        *(short8v*)&Bl[ar][ak8] = rb_l0;
        *(short8v*)&Bh[64 + ar][ak8] = rb_h1;
        *(short8v*)&Bl[64 + ar][ak8] = rb_l1;
        __syncthreads();
        if (k0 + 32 < 512){
            ra_h  = *(const short8v*)(agH + k0 + 32);
            ra_l  = *(const short8v*)(agL + k0 + 32);
            rb_h0 = *(const short8v*)(bgH0 + k0 + 32);
            rb_l0 = *(const short8v*)(bgL0 + k0 + 32);
            rb_h1 = *(const short8v*)(bgH1 + k0 + 32);
            rb_l1 = *(const short8v*)(bgL1 + k0 + 32);
        }
        short8v af_h[2], af_l[2];
#pragma unroll
        for (int mf = 0; mf < 2; ++mf){
            af_h[mf] = *(const short8v*)&Ah[wy*32 + mf*16 + l15][lk];
            af_l[mf] = *(const short8v*)&Al[wy*32 + mf*16 + l15][lk];
        }
#pragma unroll
        for (int nf = 0; nf < 4; ++nf){
            short8v bfh = *(const short8v*)&Bh[wx*64 + nf*16 + l15][lk];
            short8v bfl = *(const short8v*)&Bl[wx*64 + nf*16 + l15][lk];
            MFMA3(acc[0][nf], af_h[0], af_l[0], bfh, bfl);
            MFMA3(acc[1][nf], af_h[1], af_l[1], bfh, bfl);
        }
    }
    if (isL){
        float bov[4];
#pragma unroll
        for (int nf = 0; nf < 4; ++nf) bov[nf] = bo[nbase + wx*64 + nf*16 + l15];
#pragma unroll
        for (int mf = 0; mf < 2; ++mf){
#pragma unroll
            for (int r = 0; r < 4; ++r){
                int row = m0 + wy*32 + mf*16 + rg*4 + r;
                float* crow = logits + (size_t)row * (NSTEP * (size_t)V_);
                unsigned long long best = 0ULL;
#pragma unroll
                for (int nf = 0; nf < 4; ++nf){
                    int col = nbase + wx*64 + nf*16 + l15;
                    float v = acc[mf][nf][r] + bov[nf];
                    crow[col] = v;
                    unsigned long long key = ((unsigned long long)fkey(v) << 32) | (unsigned)(4095 - col);
                    if (key > best) best = key;
                }
#pragma unroll
                for (int off = 1; off < 16; off <<= 1){
                    unsigned long long o = __shfl_xor(best, off);
                    if (o > best) best = o;
                }
                if (l15 == 0) atomicMax(&P[row], best);
            }
        }
    } else {
#pragma unroll
        for (int mf = 0; mf < 2; ++mf)
#pragma unroll
            for (int nf = 0; nf < 4; ++nf)
#pragma unroll
                for (int r = 0; r < 4; ++r){
                    int row = m0 + wy*32 + mf*16 + rg*4 + r;
                    int col = nbase + wx*64 + nf*16 + l15;
                    gh[(size_t)row*1536 + col] = acc[mf][nf][r];
                }
    }
}

__global__ __launch_bounds__(256) void final_pred(const unsigned long long* __restrict__ P,
                                                  float* __restrict__ preds){
    int b = threadIdx.x;
    int w = 4095 - (int)(P[b] & 0xFFFFFFFFull);
    if (w < 0) w = 0; if (w > 4095) w = 4095;
    preds[b*NSTEP + (NSTEP-1)] = (float)w;
}

extern "C" void kernel_launch(void* const* d_in, const int* in_sizes, int n_in,
                              void* d_out, int out_size, void* d_ws, size_t ws_size,
                              hipStream_t stream){
    const float* elhs = (const float*)d_in[0];
    const float* enc  = (const float*)d_in[1];
    const float* emb  = (const float*)d_in[3];
    const float* W1   = (const float*)d_in[4];
    const float* W2   = (const float*)d_in[6];
    const float* W3   = (const float*)d_in[8];
    const float* W4   = (const float*)d_in[10];
    const float* Ww   = (const float*)d_in[12];
    const float* Wih  = (const float*)d_in[13];
    const float* bih  = (const float*)d_in[14];
    const float* Whh  = (const float*)d_in[15];
    const float* bhh  = (const float*)d_in[16];
    const float* Wo   = (const float*)d_in[17];
    const float* bo   = (const float*)d_in[18];

    float* out = (float*)d_out;
    float* preds = out + (size_t)B_ * NSTEP * V_;

    float* ws = (float*)d_ws;
    float* Eproj  = ws;  ws += (size_t)V_ * 1536;
    float* gictx  = ws;  ws += (size_t)B_ * 1536;
    float* ctx    = ws;  ws += B_ * H_;
    float* scores = ws;  ws += B_ * S_;
    float* t1     = ws;  ws += 512;
    float* t2     = ws;  ws += 512;
    float* weff   = ws;  ws += 512;
    float* Hf     = ws;  ws += 2 * B_ * H_;
    float* ghbuf  = ws;  ws += B_ * 1536;
    u16* WoT_hi = (u16*)ws;  ws += (size_t)V_ * 512 / 2;
    u16* WoT_lo = (u16*)ws;  ws += (size_t)V_ * 512 / 2;
    u16* WhhHi  = (u16*)ws;  ws += 1536 * 512 / 2;
    u16* WhhLo  = (u16*)ws;  ws += 1536 * 512 / 2;
    u16* Sh     = (u16*)ws;  ws += B_ * H_ / 2;
    u16* Sl     = (u16*)ws;  ws += B_ * H_ / 2;
    unsigned long long* P = (unsigned long long*)ws;   // 27*256 u64

    // big one-time splits parked in d_out head (fully consumed by eproj before logits writes)
    u16* EmbHi  = (u16*)d_out;                       // 4096x1024
    u16* EmbLo  = EmbHi + (size_t)V_*1024;
    u16* WihLHi = EmbLo + (size_t)V_*1024;           // 1536x1024 compact
    u16* WihLLo = WihLHi + (size_t)1536*1024;

    // all one-time transforms in ONE kernel (block-range dispatch)
    prep_all<<<7054, 256, 0, stream>>>(Whh, Wo, emb, Wih, elhs,
                                       WhhHi, WhhLo, WoT_hi, WoT_lo,
                                       EmbHi, EmbLo, WihLHi, WihLLo,
                                       Sh, Sl, (unsigned*)P, NSTEP*256*2);

    // front: collapsed attention (h-independent), context, gi_ctx, Eproj
    matvec512<<<512, 64, 0, stream>>>(W4, Ww, t1);
    matvec512<<<512, 64, 0, stream>>>(W3, t1, t2);
    matvec512<<<512, 64, 0, stream>>>(W2, t2, t1);
    matvec512<<<512, 64, 0, stream>>>(W1, t1, weff);
    score_kernel<<<(B_*S_)/4, 256, 0, stream>>>(enc, weff, scores);
    softmax_ctx<<<B_, 512, 0, stream>>>(enc, scores, ctx);
    { dim3 g(B_/32, 1536/64);
      gemm_abt<32><<<g, 256, 0, stream>>>(ctx, 512, Wih + 1024, 1536, bih, gictx, 1536, 512); }
    { dim3 g(1536/64, V_/64);
      eproj_u16<<<g, 256, 0, stream>>>(EmbHi, EmbLo, WihLHi, WihLLo, Eproj); }

    // gh_0 = h0 @ Whh^T  (gh-only step_mm)
    { dim3 g(4, 12);
      step_mm<<<g, 256, 0, stream>>>(Sh, Sl, WoT_hi, WoT_lo, WhhHi, WhhLo, bo,
                                     out, P, ghbuf, 0); }

    for (int t = 0; t < NSTEP; ++t){
        const float* hr = (t == 0) ? elhs : (Hf + (size_t)((t-1) & 1) * (B_*H_));
        float* hw = Hf + (size_t)(t & 1) * (B_*H_);
        const unsigned long long* Pprev = P + (size_t)(t > 0 ? t-1 : 0) * 256;
        gru_pointwise<<<128, 256, 0, stream>>>(ghbuf, Eproj, gictx, bhh, hr, hw,
                                               Sh, Sl, Pprev, preds, t);
        dim3 g(4, 32 + 12);
        step_mm<<<g, 256, 0, stream>>>(Sh, Sl, WoT_hi, WoT_lo, WhhHi, WhhLo, bo,
                                       out + (size_t)t * V_, P + (size_t)t*256, ghbuf, 32);
    }
    final_pred<<<1, 256, 0, stream>>>(P + (size_t)(NSTEP-1)*256, preds);
}